// Round 6
// baseline (483.934 us; speedup 1.0000x reference)
//
#include <hip/hip_runtime.h>
#include <hip/hip_bf16.h>

#define NB   64
#define NC   1024
#define NQ   128
#define DIMD 512
#define BK   64
#define NKC  (DIMD / BK)   // 8 K-chunks
#define LDKB (BK + 8)      // Bs row pitch in shorts

using short8  = __attribute__((ext_vector_type(8))) short;
using short4v = __attribute__((ext_vector_type(4))) short;
using f32x4   = __attribute__((ext_vector_type(4))) float;

__device__ inline float dot4(float4 a, float4 b) {
    return a.x * b.x + a.y * b.y + a.z * b.z + a.w * b.w;
}
__device__ inline short4v pk4(float a, float b, float c, float d) {
    union { __hip_bfloat162 h[2]; short4v s; } x;
    x.h[0] = __float22bfloat162_rn(make_float2(a, b));
    x.h[1] = __float22bfloat162_rn(make_float2(c, d));
    return x.s;
}

// ---------------------------------------------------------------------------
// K1 col-strip GEMM: block (b, jg) computes sim[i, jg*16 + 0..16) for ALL
// i in [0,1024) -> Z_j complete in-block -> r_i partials, no sim spill.
// 256 threads = 4 waves; wave w owns rows [w*256, w*256+256) as 16 MFMA
// row-tiles (acc = 16 x f32x4 = exp values kept in regs).
// Same-batch blocks share an XCD (linear%8 = b%8): 8x ctx re-read is L2-hit.
// ---------------------------------------------------------------------------
__global__ __launch_bounds__(256) void colgemm_kernel(
    const float* __restrict__ ctx, const float* __restrict__ qry,
    const float* __restrict__ w0, float* __restrict__ rpart)
{
    __shared__ __attribute__((aligned(16))) short Bs[16][LDKB]; // bf16(wm*q)
    __shared__ __attribute__((aligned(16))) float w0L[3 * DIMD];
    __shared__ float cwL[NC];          // 4 KB: cw for all 1024 rows
    __shared__ float qwL[16];
    __shared__ float zL[4][16];

    const int tid  = threadIdx.x;
    const int b    = blockIdx.x;
    const int jg   = blockIdx.y;
    const int w    = tid >> 6;
    const int lane = tid & 63;
    const int n16  = lane & 15, qd = lane >> 4;

    for (int idx = tid; idx < 3 * DIMD; idx += 256) w0L[idx] = w0[idx];

    f32x4 acc[16];
#pragma unroll
    for (int rt = 0; rt < 16; rt++)
#pragma unroll
        for (int e = 0; e < 4; e++) acc[rt][e] = 0.f;

    // B staging thread map: row = tid>>4 (16 q rows), k4 = (tid&15)*4
    const int brow = tid >> 4, bk4 = (tid & 15) * 4;
    const float* qRow = qry + ((size_t)(b * NQ + jg * 16 + brow)) * DIMD + bk4;
    float qwp = 0.f;

    // A path: lane reads rows w*256 + rt*16 + n16, k-window ks*32 + qd*8
    const float* cBase = ctx + ((size_t)(b * NC + w * 256 + n16)) * DIMD + qd * 8;
    float cwp[16];
#pragma unroll
    for (int rt = 0; rt < 16; rt++) cwp[rt] = 0.f;

    __syncthreads();   // w0L ready

    for (int kc = 0; kc < NKC; kc++) {
        const int k0 = kc * BK;
        // ---- stage B chunk (wm folded into q) + qw dot ----
        {
            float4 q  = *(const float4*)(qRow + k0);
            float4 wq = *(const float4*)&w0L[DIMD + k0 + bk4];
            float4 wm = *(const float4*)&w0L[2 * DIMD + k0 + bk4];
            qwp += dot4(q, wq);
            *(short4v*)&Bs[brow][bk4] = pk4(q.x * wm.x, q.y * wm.y, q.z * wm.z, q.w * wm.w);
        }
        __syncthreads();
#pragma unroll
        for (int ks = 0; ks < 2; ks++) {
            const int kw = k0 + ks * 32 + qd * 8;   // lane's 8-float k-window
            float4 wc0 = *(const float4*)&w0L[kw];
            float4 wc1 = *(const float4*)&w0L[kw + 4];
            short8 bfr = *(const short8*)&Bs[n16][ks * 32 + qd * 8];
#pragma unroll
            for (int rt = 0; rt < 16; rt++) {
                const float* ap = cBase + (size_t)rt * 16 * DIMD + k0 + ks * 32;
                float4 a0 = *(const float4*)(ap);
                float4 a1 = *(const float4*)(ap + 4);
                cwp[rt] += dot4(a0, wc0) + dot4(a1, wc1);
                union { short4v s4[2]; short8 s8; } af;
                af.s4[0] = pk4(a0.x, a0.y, a0.z, a0.w);
                af.s4[1] = pk4(a1.x, a1.y, a1.z, a1.w);
                acc[rt] = __builtin_amdgcn_mfma_f32_16x16x32_bf16(af.s8, bfr, acc[rt], 0, 0, 0);
            }
        }
        __syncthreads();   // Bs consumed before next stage
    }

    // qw reduce: 16 threads (same brow) are contiguous lanes within a wave
    {
        float q = qwp;
#pragma unroll
        for (int off = 1; off < 16; off <<= 1) q += __shfl_xor(q, off);
        if ((tid & 15) == 0 && w == (brow >> 2)) qwL[brow] = q;  // one writer per row
    }
    // cw reduce over qd lanes (k-halves/quarters), write all 1024 rows
#pragma unroll
    for (int rt = 0; rt < 16; rt++) {
        float c = cwp[rt];
        c += __shfl_xor(c, 16);
        c += __shfl_xor(c, 32);
        if (qd == 0) cwL[w * 256 + rt * 16 + n16] = c;
    }
    __syncthreads();

    // exp in-place + per-wave column Z partial.
    // C/D layout: col = n16 (local j), row = qd*4 + reg (+ rt*16 + w*256)
    const float qwv = qwL[n16];
    float zp = 0.f;
#pragma unroll
    for (int rt = 0; rt < 16; rt++) {
        const int rbase = w * 256 + rt * 16 + qd * 4;
#pragma unroll
        for (int rg = 0; rg < 4; rg++) {
            float e = __expf(acc[rt][rg] + cwL[rbase + rg] + qwv);
            acc[rt][rg] = e;
            zp += e;
        }
    }
    zp += __shfl_xor(zp, 16);
    zp += __shfl_xor(zp, 32);
    if (qd == 0) zL[w][n16] = zp;
    __syncthreads();
    const float iz = 1.0f / (zL[0][n16] + zL[1][n16] + zL[2][n16] + zL[3][n16]);

    // r_i partial for this block's 16 cols: reduce e*iz over n16 lanes
    float* rp = rpart + ((size_t)(b * 8 + jg)) * NC;
#pragma unroll
    for (int rt = 0; rt < 16; rt++) {
        f32x4 rv;
#pragma unroll
        for (int rg = 0; rg < 4; rg++) {
            float v = acc[rt][rg] * iz;
#pragma unroll
            for (int off = 1; off < 16; off <<= 1) v += __shfl_xor(v, off);
            rv[rg] = v;
        }
        if (n16 == 0)
            *(f32x4*)&rp[w * 256 + rt * 16 + qd * 4] = rv;
    }
}

// ---------------------------------------------------------------------------
// K2: block (b, dg): rfull_i = sum_jg rpart; Brow[d] = sum_i rfull_i*ctx[i][d]
// for d in [dg*64, dg*64+64); also Arow slice. ctx/qry slices are L2-hot.
// ---------------------------------------------------------------------------
__global__ __launch_bounds__(256) void brow_kernel(
    const float* __restrict__ ctx, const float* __restrict__ qry,
    const float* __restrict__ rpart, float* __restrict__ browG,
    float* __restrict__ arowG)
{
    __shared__ float rfullL[NC];
    __shared__ float bredL[4][64];
    __shared__ float aredL[4][64];

    const int tid = threadIdx.x;
    const int b = blockIdx.x, dg = blockIdx.y;

#pragma unroll
    for (int g = 0; g < 4; g++) {
        const int i = g * 256 + tid;
        float s = 0.f;
#pragma unroll
        for (int t = 0; t < 8; t++)
            s += rpart[((size_t)(b * 8 + t)) * NC + i];
        rfullL[i] = s;
    }
    __syncthreads();

    const int d = dg * 64 + (tid & 63);
    const int g = tid >> 6;
    {
        float s = 0.f;
        const float* cb = ctx + ((size_t)(b * NC + g * 256)) * DIMD + d;
        for (int ii = 0; ii < 256; ii++)
            s += rfullL[g * 256 + ii] * cb[(size_t)ii * DIMD];
        bredL[g][tid & 63] = s;
    }
    {
        float s = 0.f;
        const float* qb = qry + ((size_t)(b * NQ + g * 32)) * DIMD + d;
        for (int j = 0; j < 32; j++)
            s += qb[(size_t)j * DIMD];
        aredL[g][tid & 63] = s;
    }
    __syncthreads();
    if (tid < 64) {
        browG[(size_t)b * DIMD + dg * 64 + tid] =
            bredL[0][tid] + bredL[1][tid] + bredL[2][tid] + bredL[3][tid];
        arowG[(size_t)b * DIMD + dg * 64 + tid] =
            aredL[0][tid] + aredL[1][tid] + aredL[2][tid] + aredL[3][tid];
    }
}

// ---------------------------------------------------------------------------
// K3: broadcast-write A (=arow) and B (=brow). Grid (NB, 32), block 256.
// ---------------------------------------------------------------------------
__global__ void broadcast_out(const float* __restrict__ arowG, const float* __restrict__ browG,
                              float* __restrict__ out)
{
    const int b = blockIdx.x, ic = blockIdx.y;
    const int t = threadIdx.x;
    const int half = t >> 7;          // 0 -> A, 1 -> B (wave-uniform)
    const int l = t & 127;
    const int d0 = l * 4;
    float4 val;
    if (half == 0) val = *(const float4*)&arowG[(size_t)b * DIMD + d0];
    else           val = *(const float4*)&browG[(size_t)b * DIMD + d0];
    size_t base = (size_t)half * ((size_t)NB * NC * DIMD)
                + ((size_t)b * NC + (size_t)ic * 32) * DIMD + d0;
    for (int i = 0; i < 32; i++)
        *(float4*)&out[base + (size_t)i * DIMD] = val;
}

extern "C" void kernel_launch(void* const* d_in, const int* in_sizes, int n_in,
                              void* d_out, int out_size, void* d_ws, size_t ws_size,
                              hipStream_t stream)
{
    const float* ctx = (const float*)d_in[0];  // (64,1024,512) f32
    const float* qry = (const float*)d_in[1];  // (64,128,512) f32
    const float* w0  = (const float*)d_in[2];  // (1536,) f32
    float* out = (float*)d_out;
    char*  ws  = (char*)d_ws;

    float* rpart = (float*)(ws);              // 64*8*1024 f32 = 2 MB
    float* browG = (float*)(ws + (4u << 20)); // 128 KB
    float* arowG = (float*)(ws + (5u << 20)); // 128 KB

    colgemm_kernel<<<dim3(NB, 8), 256, 0, stream>>>(ctx, qry, w0, rpart);
    brow_kernel<<<dim3(NB, 8), 256, 0, stream>>>(ctx, qry, rpart, browG, arowG);
    broadcast_out<<<dim3(NB, 32), 256, 0, stream>>>(arowG, browG, out);
}

// Round 7
// 449.829 us; speedup vs baseline: 1.0758x; 1.0758x over previous
//
#include <hip/hip_runtime.h>
#include <hip/hip_bf16.h>

#define NB   64
#define NC   1024
#define NQ   128
#define DIMD 512
#define BK   64
#define NKC  (DIMD / BK)   // 8 K-chunks
#define TM   128           // rows per context tile
#define NTILE (NC / TM)    // 8 tiles
#define BROWS 144          // 128 q-rows + wc row (128) + 15 zero rows

using short8  = __attribute__((ext_vector_type(8))) short;
using short4v = __attribute__((ext_vector_type(4))) short;
using f32x4   = __attribute__((ext_vector_type(4))) float;
typedef __fp16 half2v __attribute__((ext_vector_type(2)));

__device__ inline float dot4(float4 a, float4 b) {
    return a.x * b.x + a.y * b.y + a.z * b.z + a.w * b.w;
}
__device__ inline short8 pk8(float4 a, float4 b) {
    union { __hip_bfloat162 h[4]; short8 s; } x;
    x.h[0] = __float22bfloat162_rn(make_float2(a.x, a.y));
    x.h[1] = __float22bfloat162_rn(make_float2(a.z, a.w));
    x.h[2] = __float22bfloat162_rn(make_float2(b.x, b.y));
    x.h[3] = __float22bfloat162_rn(make_float2(b.z, b.w));
    return x.s;
}

// ---------------------------------------------------------------------------
// K1: bf16 MFMA GEMM -> fp16 sim spill + per-tile column sum_exp.
//  - A = raw bf16(ctx), loaded DIRECTLY from global fp32 per fragment
//    (no A-LDS, no A staging VALU, one barrier/chunk).
//  - B = bf16(wm * q) in LDS, XOR-granule swizzle (bank-floor), plus a
//    129th row = bf16(wc): the MFMA computes cw_i in an extra acc tile.
//  - qw via per-thread dots during B staging (8-lane reduce at end).
// Grid (NB, NTILE) -> same-batch blocks share an XCD (linear%8 = b%8).
// ---------------------------------------------------------------------------
__global__ __launch_bounds__(256) void gemm_stats(
    const float* __restrict__ ctx, const float* __restrict__ qry,
    const float* __restrict__ w0, float* __restrict__ stats,
    unsigned short* __restrict__ simh)
{
    __shared__ __attribute__((aligned(16))) short Bs[BROWS * BK]; // swizzled granules
    __shared__ __attribute__((aligned(16))) float w0L[3 * DIMD];
    __shared__ float cwL[TM], qwL[NQ], sL[2][NQ];

    const int tid  = threadIdx.x;
    const int b    = blockIdx.x;
    const int bt   = blockIdx.y;
    const int i0   = bt * TM;
    const int w    = tid >> 6;
    const int lane = tid & 63;
    const int wr   = w >> 1, wcg = w & 1;
    const int RB   = wr * 64, CB = wcg * 64;
    const int n16  = lane & 15, qd = lane >> 4;

    for (int idx = tid; idx < 3 * DIMD; idx += 256) w0L[idx] = w0[idx];
    // zero rows 129..143 once (cols 129..143 of the cw tile read zeros)
    for (int idx = tid; idx < (BROWS - 129) * BK / 2; idx += 256)
        ((unsigned*)&Bs[129 * BK])[idx] = 0u;

    f32x4 acc[4][4], cwacc[4];
#pragma unroll
    for (int ri = 0; ri < 4; ri++) {
#pragma unroll
        for (int ci = 0; ci < 4; ci++)
#pragma unroll
            for (int e = 0; e < 4; e++) acc[ri][ci][e] = 0.f;
#pragma unroll
        for (int e = 0; e < 4; e++) cwacc[ri][e] = 0.f;
    }

    // B staging map: 4 iters, row = it*32 + (tid>>3), granule kg = tid&7
    const int srow = tid >> 3, kg = tid & 7;
    float qwp[4] = {0.f, 0.f, 0.f, 0.f};

    // A row pointers (direct global fragments)
    const float* aBase[4];
#pragma unroll
    for (int ri = 0; ri < 4; ri++)
        aBase[ri] = ctx + ((size_t)(b * NC + i0 + RB + ri * 16 + n16)) * DIMD + qd * 8;

    for (int kc = 0; kc < NKC; kc++) {
        const int k0 = kc * BK;
        __syncthreads();   // prev MFMA done reading Bs (covers w0L/zero on kc=0)
        // ---- stage B chunk: rows it*32+srow, granule kg (8 k's) ----
#pragma unroll
        for (int it = 0; it < 4; it++) {
            const int row = it * 32 + srow;
            const int col = k0 + kg * 8;
            float4 q0 = *(const float4*)(qry + ((size_t)(b * NQ + row)) * DIMD + col);
            float4 q1 = *(const float4*)(qry + ((size_t)(b * NQ + row)) * DIMD + col + 4);
            float4 wq0 = *(const float4*)&w0L[DIMD + col];
            float4 wq1 = *(const float4*)&w0L[DIMD + col + 4];
            float4 wm0 = *(const float4*)&w0L[2 * DIMD + col];
            float4 wm1 = *(const float4*)&w0L[2 * DIMD + col + 4];
            qwp[it] += dot4(q0, wq0) + dot4(q1, wq1);
            float4 m0, m1;
            m0.x = q0.x * wm0.x; m0.y = q0.y * wm0.y; m0.z = q0.z * wm0.z; m0.w = q0.w * wm0.w;
            m1.x = q1.x * wm1.x; m1.y = q1.y * wm1.y; m1.z = q1.z * wm1.z; m1.w = q1.w * wm1.w;
            *(short8*)&Bs[row * BK + ((kg ^ (row & 7)) * 8)] = pk8(m0, m1);
        }
        if (tid < 8) {       // row 128 = wc (raw)
            const int col = k0 + tid * 8;
            float4 c0 = *(const float4*)&w0L[col];
            float4 c1 = *(const float4*)&w0L[col + 4];
            *(short8*)&Bs[128 * BK + (tid * 8)] = pk8(c0, c1);   // row&7 == 0
        }
        __syncthreads();
        // ---- MFMA ----
#pragma unroll
        for (int ks = 0; ks < 2; ks++) {
            const int g = ks * 4 + qd;
            short8 af[4], bfr[4];
#pragma unroll
            for (int ri = 0; ri < 4; ri++) {
                const float* ap = aBase[ri] + k0 + ks * 32;
                float4 a0 = *(const float4*)(ap);
                float4 a1 = *(const float4*)(ap + 4);
                af[ri] = pk8(a0, a1);
            }
#pragma unroll
            for (int ci = 0; ci < 4; ci++) {
                const int rowb = CB + ci * 16 + n16;
                bfr[ci] = *(const short8*)&Bs[rowb * BK + ((g ^ (rowb & 7)) * 8)];
            }
#pragma unroll
            for (int ri = 0; ri < 4; ri++)
#pragma unroll
                for (int ci = 0; ci < 4; ci++)
                    acc[ri][ci] = __builtin_amdgcn_mfma_f32_16x16x32_bf16(
                        af[ri], bfr[ci], acc[ri][ci], 0, 0, 0);
            if (wcg == 0) {  // cw tile: B rows 128..143 (row 128 = wc, rest zero)
                const int rowb = 128 + n16;
                short8 bcw = *(const short8*)&Bs[rowb * BK + ((g ^ (rowb & 7)) * 8)];
#pragma unroll
                for (int ri = 0; ri < 4; ri++)
                    cwacc[ri] = __builtin_amdgcn_mfma_f32_16x16x32_bf16(
                        af[ri], bcw, cwacc[ri], 0, 0, 0);
            }
        }
    }

    // qw reduce: 8 lanes (tid&7) per row, contiguous within a wave
#pragma unroll
    for (int it = 0; it < 4; it++) {
        float q = qwp[it];
#pragma unroll
        for (int off = 1; off < 8; off <<= 1) q += __shfl_xor(q, off);
        if ((tid & 7) == 0) qwL[it * 32 + srow] = q;
    }
    // cw from cwacc: C-layout col = n16 (only col 0 valid), row = qd*4+reg
    if (wcg == 0 && n16 == 0) {
#pragma unroll
        for (int ri = 0; ri < 4; ri++)
#pragma unroll
            for (int rg = 0; rg < 4; rg++)
                cwL[RB + ri * 16 + qd * 4 + rg] = cwacc[ri][rg];
    }
    __syncthreads();

    // Epilogue: v = acc + cw_i + qw_j; fp16 sim spill (col-major) + col sum_exp.
#pragma unroll
    for (int ci = 0; ci < 4; ci++) {
        const int col = CB + ci * 16 + n16;
        const float qwv = qwL[col];
        unsigned short* simCol = simh + ((size_t)(b * NTILE + bt) * NQ + col) * TM;
        float s = 0.f;
#pragma unroll
        for (int ri = 0; ri < 4; ri++) {
            const int rbase = RB + ri * 16 + qd * 4;
            float v0 = acc[ri][ci][0] + cwL[rbase + 0] + qwv;
            float v1 = acc[ri][ci][1] + cwL[rbase + 1] + qwv;
            float v2 = acc[ri][ci][2] + cwL[rbase + 2] + qwv;
            float v3 = acc[ri][ci][3] + cwL[rbase + 3] + qwv;
            s += __expf(v0) + __expf(v1) + __expf(v2) + __expf(v3);
            half2v h01 = __builtin_amdgcn_cvt_pkrtz(v0, v1);
            half2v h23 = __builtin_amdgcn_cvt_pkrtz(v2, v3);
            uint2 pk;
            pk.x = __builtin_bit_cast(unsigned, h01);
            pk.y = __builtin_bit_cast(unsigned, h23);
            *(uint2*)&simCol[rbase] = pk;
        }
        s += __shfl_xor(s, 16);
        s += __shfl_xor(s, 32);
        if (qd == 0) sL[wr][col] = s;
    }
    __syncthreads();
    if (tid < NQ)
        stats[(size_t)(b * NTILE + bt) * NQ + tid] = sL[0][tid] + sL[1][tid];
}

// ---------------------------------------------------------------------------
// K2: iz (combine fused), r_i = sum_j exp(sim)*iz_j, bpart = sum_i r_i ctx[i];
// bt==0 blocks also compute arow = sum_j qry[j]. ctx/qry reads are L3-hot.
// Grid (NB, NTILE), block 256.
// ---------------------------------------------------------------------------
__global__ __launch_bounds__(256) void rb_kernel(
    const float* __restrict__ ctx, const float* __restrict__ qry,
    const unsigned short* __restrict__ simh, const float* __restrict__ stats,
    float* __restrict__ bpart, float* __restrict__ arow)
{
    __shared__ __attribute__((aligned(16))) unsigned short simL[NQ * TM];
    __shared__ float izL[NQ];
    __shared__ float rpart[2][TM];
    __shared__ float rfin[TM];

    const int tid = threadIdx.x;
    const int b = blockIdx.x, bt = blockIdx.y;
    const int i0 = bt * TM;

    if (tid < NQ) {
        float s = 0.f;
        for (int t = 0; t < NTILE; t++)
            s += stats[(size_t)(b * NTILE + t) * NQ + tid];
        izL[tid] = 1.0f / s;
    }
    const unsigned short* tileSrc = simh + (size_t)(b * NTILE + bt) * NQ * TM;
#pragma unroll
    for (int it = 0; it < 8; it++) {
        const int idx = (tid + it * 256) * 8;   // 16B per thread
        *(uint4*)&simL[idx] = *(const uint4*)&tileSrc[idx];
    }
    __syncthreads();

    const int i = tid & 127, jh = tid >> 7;
    float r = 0.f;
    for (int j2 = 0; j2 < 64; j2++) {
        const int j = jh * 64 + j2;
        __fp16 hv = __builtin_bit_cast(__fp16, simL[j * TM + i]);
        r += __expf((float)hv) * izL[j];
    }
    rpart[jh][i] = r;
    __syncthreads();
    if (tid < TM) rfin[tid] = rpart[0][tid] + rpart[1][tid];
    __syncthreads();

    const int d0 = tid * 2;
    {
        float bx = 0.f, by = 0.f;
        const float* cb2 = ctx + ((size_t)(b * NC + i0)) * DIMD + d0;
        for (int ii = 0; ii < TM; ii++) {
            float  rv = rfin[ii];
            float2 cv = *(const float2*)(cb2 + (size_t)ii * DIMD);
            bx += rv * cv.x; by += rv * cv.y;
        }
        float* bp = bpart + (size_t)(b * NTILE + bt) * DIMD + d0;
        bp[0] = bx; bp[1] = by;
    }
    if (bt == 0) {
        float ax = 0.f, ay = 0.f;
        const float* qb = qry + (size_t)b * NQ * DIMD + d0;
        for (int j = 0; j < NQ; j++) {
            float2 v = *(const float2*)(qb + (size_t)j * DIMD);
            ax += v.x; ay += v.y;
        }
        float2 rr; rr.x = ax; rr.y = ay;
        *(float2*)&arow[(size_t)b * DIMD + d0] = rr;
    }
}

// ---------------------------------------------------------------------------
// K3: reduce bpart + broadcast-write A and B. Grid (NB, 32), block 256.
// ---------------------------------------------------------------------------
__global__ void broadcast_out(const float* __restrict__ arow, const float* __restrict__ bpart,
                              float* __restrict__ out)
{
    const int b = blockIdx.x, ic = blockIdx.y;
    const int t = threadIdx.x;
    const int half = t >> 7;          // 0 -> A, 1 -> B (wave-uniform)
    const int l = t & 127;
    const int d0 = l * 4;
    float4 val;
    if (half == 0) {
        val = *(const float4*)&arow[(size_t)b * DIMD + d0];
    } else {
        val.x = val.y = val.z = val.w = 0.f;
        for (int t8 = 0; t8 < NTILE; t8++) {
            float4 v = *(const float4*)&bpart[(size_t)(b * NTILE + t8) * DIMD + d0];
            val.x += v.x; val.y += v.y; val.z += v.z; val.w += v.w;
        }
    }
    size_t base = (size_t)half * ((size_t)NB * NC * DIMD)
                + ((size_t)b * NC + (size_t)ic * 32) * DIMD + d0;
    for (int i = 0; i < 32; i++)
        *(float4*)&out[base + (size_t)i * DIMD] = val;
}

extern "C" void kernel_launch(void* const* d_in, const int* in_sizes, int n_in,
                              void* d_out, int out_size, void* d_ws, size_t ws_size,
                              hipStream_t stream)
{
    const float* ctx = (const float*)d_in[0];  // (64,1024,512) f32
    const float* qry = (const float*)d_in[1];  // (64,128,512) f32
    const float* w0  = (const float*)d_in[2];  // (1536,) f32
    float* out = (float*)d_out;
    char*  ws  = (char*)d_ws;

    float* stats = (float*)(ws);              // 64*8*128 f32 = 256 KB
    float* bpart = (float*)(ws + (1u << 20)); // 64*8*512 f32 = 1 MB
    float* arow  = (float*)(ws + (3u << 20)); // 64*512 f32   = 128 KB
    unsigned short* simh = (unsigned short*)(ws + (8u << 20)); // 16.8 MB fp16

    gemm_stats<<<dim3(NB, NTILE), 256, 0, stream>>>(ctx, qry, w0, stats, simh);
    rb_kernel<<<dim3(NB, NTILE), 256, 0, stream>>>(ctx, qry, simh, stats, bpart, arow);
    broadcast_out<<<dim3(NB, 32), 256, 0, stream>>>(arow, bpart, out);
}